// Round 10
// baseline (31.358 us; speedup 1.0000x reference)
//
#include <hip/hip_runtime.h>

// DICE multi-class loss.
//   output: [B=16, C=8, H=512, W=512] fp32
//   mask:   [B=16, H=512, W=512] int32 (labels 0..7)
// loss = 1 - sum_{b,c} dice(b,c) / (B*B),  dice = 2*(num+eps)/(den1+den2+eps)
//
// Journal:
// R4: 8 waves/CU latency-bound. R5: NT + DPP reduce, BPB=128 -> 30.66us.
// R6: per-block device fences = 6x disaster; FETCH=74MB proved partial cache
//     residency. R8 A/B: NT helps +5%. R9: BPB=64 (16 waves/CU) -> 29.58us.
// R10: stream-structure experiment. Old: 9 interleaved 1MB-strided streams
//     per block (~9000 chip-wide, poor DRAM row locality; fills with 1
//     stream/block hit 7TB/s vs our 5.7). New: block=(b, 16KB chunk),
//     channels SEQUENTIAL: one contiguous NT plane stream at a time; mask
//     chunk (16KB < 32KB L1) read with plain loads, L1-hot for c=1..7.
//     HBM exactly 144MB. 3 live accs; per-c DPP tail overlaps next c's loads.

#define BB 16
#define CC 8
#define HWPIX (512 * 512)
#define HW4 (HWPIX / 4)        // 65536 float4-quads per plane
#define NCHUNK 64              // chunks per image -> 16KB plane-chunk per pass
#define QPC (HW4 / NCHUNK)     // 1024 quads per chunk
#define NBLOCKS (BB * NCHUNK)  // 1024 blocks = 4/CU, 16 waves/CU (R9-proven)

typedef float f32x4 __attribute__((ext_vector_type(4)));
typedef int i32x4 __attribute__((ext_vector_type(4)));

// ---- DPP wave64 sum (VALU pipe only, no DS ops); total lands in lane 63 ----
template <int CTRL>
__device__ __forceinline__ float dpp_add(float x) {
    int yi = __builtin_amdgcn_update_dpp(0, __float_as_int(x), CTRL, 0xf, 0xf, true);
    return x + __int_as_float(yi);
}
__device__ __forceinline__ float wave_sum63(float x) {
    x = dpp_add<0x111>(x);   // row_shr:1
    x = dpp_add<0x112>(x);   // row_shr:2
    x = dpp_add<0x114>(x);   // row_shr:4
    x = dpp_add<0x118>(x);   // row_shr:8
    x = dpp_add<0x142>(x);   // row_bcast:15
    x = dpp_add<0x143>(x);   // row_bcast:31
    return x;
}

__global__ __launch_bounds__(256) void dice_partial(const float* __restrict__ out,
                                                    const int* __restrict__ mask,
                                                    float* __restrict__ ws) {
    const int b = blockIdx.x / NCHUNK;
    const int ch = blockIdx.x % NCHUNK;
    const f32x4* __restrict__ ov = (const f32x4*)(out + (size_t)b * CC * HWPIX);
    const i32x4* __restrict__ mv = (const i32x4*)(mask + (size_t)b * HWPIX);
    const int q0 = ch * QPC;

    const int lane = threadIdx.x & 63;
    const int wid = threadIdx.x >> 6;
    __shared__ float red[4][24];

#pragma unroll
    for (int c = 0; c < CC; ++c) {
        float num = 0.f, d1 = 0.f, d2 = 0.f;
#pragma unroll
        for (int i = 0; i < QPC / 256; ++i) {    // 4 iters: contiguous 16KB run
            const int q = q0 + i * 256 + threadIdx.x;
            const i32x4 m = mv[q];               // plain load: L1-hot for c>=1
            const f32x4 v = __builtin_nontemporal_load(&ov[c * HW4 + q]);
            d1 += v.x * v.x + v.y * v.y + v.z * v.z + v.w * v.w;
            float hx = (m.x == c) ? 1.f : 0.f;
            float hy = (m.y == c) ? 1.f : 0.f;
            float hz = (m.z == c) ? 1.f : 0.f;
            float hw = (m.w == c) ? 1.f : 0.f;
            num += hx * v.x + hy * v.y + hz * v.z + hw * v.w;
            d2 += hx + hy + hz + hw;
        }
        float a0 = wave_sum63(num);
        float a1 = wave_sum63(d1);
        float a2 = wave_sum63(d2);
        if (lane == 63) {
            red[wid][0 * 8 + c] = a0;
            red[wid][1 * 8 + c] = a1;
            red[wid][2 * 8 + c] = a2;
        }
    }
    __syncthreads();
    if (threadIdx.x < 24) {
        const int k = threadIdx.x;       // k = qy*8 + c
        const int qy = k >> 3;
        const int c = k & 7;
        float s = red[0][k] + red[1][k] + red[2][k] + red[3][k];
        // partial layout: ws[((qy*BB + b)*CC + c)*NCHUNK + chunk]
        ws[((qy * BB + b) * CC + c) * NCHUNK + ch] = s;
    }
}

// 1024 threads: 8 threads per (b,c) pair, 2 f32x4 loads per quantity.
__global__ __launch_bounds__(1024) void dice_final(const float* __restrict__ ws,
                                                   float* __restrict__ out) {
    const int t = threadIdx.x;
    const int g = t >> 3;        // (b,c) group 0..127
    const int sub = t & 7;
    const int b = g >> 3;
    const int c = g & 7;

    float acc[3] = {0.f, 0.f, 0.f};   // num, d1, d2
#pragma unroll
    for (int qy = 0; qy < 3; ++qy) {
        const f32x4* p = (const f32x4*)(ws + ((qy * BB + b) * CC + c) * NCHUNK);
#pragma unroll
        for (int i = 0; i < NCHUNK / (8 * 4); ++i) {   // 2 f32x4 per thread
            f32x4 v = p[sub + i * 8];
            acc[qy] += v.x + v.y + v.z + v.w;
        }
    }
#pragma unroll
    for (int qy = 0; qy < 3; ++qy) {
#pragma unroll
        for (int o = 4; o > 0; o >>= 1) acc[qy] += __shfl_down(acc[qy], o, 8);
    }

    __shared__ float sm[128];
    __shared__ float sm2[2];
    if (sub == 0) {
        const float eps = 1e-7f;
        sm[g] = 2.f * (acc[0] + eps) / (acc[1] + acc[2] + eps);
    }
    __syncthreads();
    if (t < 128) {
        float x = wave_sum63(sm[t]);
        if ((t & 63) == 63) sm2[t >> 6] = x;
    }
    __syncthreads();
    if (t == 0) out[0] = 1.f - (sm2[0] + sm2[1]) / ((float)BB * (float)BB);
}

extern "C" void kernel_launch(void* const* d_in, const int* in_sizes, int n_in,
                              void* d_out, int out_size, void* d_ws, size_t ws_size,
                              hipStream_t stream) {
    const float* out_probs = (const float*)d_in[0];
    const int* mask = (const int*)d_in[1];
    float* ws = (float*)d_ws;    // 3*16*8*64 floats = 96 KiB
    float* loss = (float*)d_out;

    dice_partial<<<NBLOCKS, 256, 0, stream>>>(out_probs, mask, ws);
    dice_final<<<1, 1024, 0, stream>>>(ws, loss);
}